// Round 1
// baseline (786.064 us; speedup 1.0000x reference)
//
#include <hip/hip_runtime.h>
#include <math.h>

#define T_TOK 2048
#define HD    2048
#define NEXP  64
#define KTOP  8
#define FD    768
#define CAPE  512

typedef float  f32x4 __attribute__((ext_vector_type(4)));
typedef __bf16 bf16x8 __attribute__((ext_vector_type(8)));

__device__ __forceinline__ unsigned short f2bf(float f) {
  union { float f; unsigned u; } v; v.f = f;
  unsigned r = v.u + 0x7fffu + ((v.u >> 16) & 1u);
  return (unsigned short)(r >> 16);
}

__device__ __forceinline__ void load_lds16(const void* g, void* l) {
  __builtin_amdgcn_global_load_lds(
      (const __attribute__((address_space(1))) unsigned int*)g,
      (__attribute__((address_space(3))) unsigned int*)l, 16, 0, 0);
}

// ---------------- Kernel 1: router (4 tokens per block) ----------------
__global__ __launch_bounds__(256) void router_kernel(
    const float* __restrict__ x, const float* __restrict__ rw,
    int* __restrict__ cnt, int* __restrict__ tok_list, float* __restrict__ w_list)
{
  const int t = threadIdx.x;
  const int tb = blockIdx.x * 4;
  __shared__ float xs[4][HD];
  __shared__ float lg[4][NEXP];

  const float4* xsrc = (const float4*)(x + (size_t)tb * HD);
  float4* xdst = (float4*)&xs[0][0];
  for (int i = t; i < 4 * HD / 4; i += 256) xdst[i] = xsrc[i];
  __syncthreads();

  {
    const int e = t >> 2, q = t & 3;
    const float* wrow = rw + (size_t)e * HD;
    float a0 = 0.f, a1 = 0.f, a2 = 0.f, a3 = 0.f;
    for (int i = 0; i < HD / 16; ++i) {
      int h = (i * 4 + q) * 4;
      float4 wv = *(const float4*)(wrow + h);
      float4 x0 = *(const float4*)&xs[0][h];
      float4 x1 = *(const float4*)&xs[1][h];
      float4 x2 = *(const float4*)&xs[2][h];
      float4 x3 = *(const float4*)&xs[3][h];
      a0 += wv.x*x0.x + wv.y*x0.y + wv.z*x0.z + wv.w*x0.w;
      a1 += wv.x*x1.x + wv.y*x1.y + wv.z*x1.z + wv.w*x1.w;
      a2 += wv.x*x2.x + wv.y*x2.y + wv.z*x2.z + wv.w*x2.w;
      a3 += wv.x*x3.x + wv.y*x3.y + wv.z*x3.z + wv.w*x3.w;
    }
    a0 += __shfl_xor(a0, 1); a0 += __shfl_xor(a0, 2);
    a1 += __shfl_xor(a1, 1); a1 += __shfl_xor(a1, 2);
    a2 += __shfl_xor(a2, 1); a2 += __shfl_xor(a2, 2);
    a3 += __shfl_xor(a3, 1); a3 += __shfl_xor(a3, 2);
    if (q == 0) { lg[0][e] = a0; lg[1][e] = a1; lg[2][e] = a2; lg[3][e] = a3; }
  }
  __syncthreads();

  const int wid = t >> 6, lane = t & 63;
  float v = lg[wid][lane];
  float mx = v;
  for (int o = 32; o; o >>= 1) mx = fmaxf(mx, __shfl_xor(mx, o));
  float p = expf(v - mx);
  float s = p;
  for (int o = 32; o; o >>= 1) s += __shfl_xor(s, o);
  float prob = p / s;

  float r = prob;
  float wk[KTOP]; int ik[KTOP]; float wsum = 0.f;
  #pragma unroll
  for (int k = 0; k < KTOP; ++k) {
    float bv = r; int bl = lane;
    for (int o = 32; o; o >>= 1) {
      float ov = __shfl_xor(bv, o); int ol = __shfl_xor(bl, o);
      if (ov > bv || (ov == bv && ol < bl)) { bv = ov; bl = ol; }
    }
    wk[k] = bv; ik[k] = bl; wsum += bv;
    if (lane == bl) r = -1.f;
  }
  if (lane == 0) {
    float inv = 1.f / (wsum + 1e-20f);
    int token = tb + wid;
    #pragma unroll
    for (int k = 0; k < KTOP; ++k) {
      int ex = ik[k];
      int pos = atomicAdd(&cnt[ex], 1);
      if (pos < CAPE) {
        tok_list[ex * CAPE + pos] = token;
        w_list[ex * CAPE + pos] = wk[k] * inv;
      }
    }
  }
}

// ---------------- Kernel 2: f32 -> bf16 convert of hidden_states ----------------
__global__ __launch_bounds__(256) void cvt_kernel(
    const float* __restrict__ x, unsigned short* __restrict__ xb)
{
  int i = blockIdx.x * 256 + threadIdx.x;   // exactly T*H/4 threads
  float4 v = ((const float4*)x)[i];
  ushort4 o = make_ushort4(f2bf(v.x), f2bf(v.y), f2bf(v.z), f2bf(v.w));
  ((ushort4*)xb)[i] = o;
}

// ---------------- Kernel 3: gate/up GEMM + SiLU -> hmid (bf16) ----------------
__global__ __launch_bounds__(256) void gateup_kernel(
    const unsigned short* __restrict__ xb,
    const float* __restrict__ wg, const float* __restrict__ wu,
    const int* __restrict__ cnt, const int* __restrict__ tok_list,
    unsigned short* __restrict__ hmid)
{
  const int nt = blockIdx.x, mt = blockIdx.y, e = blockIdx.z;
  int ne = cnt[e]; ne = ne < CAPE ? ne : CAPE;
  if (mt * 128 >= ne) return;
  const int t = threadIdx.x, lane = t & 63, wid = t >> 6;
  const int wr = wid >> 1, wc = wid & 1;

  __shared__ __align__(16) unsigned short A[128 * 64];   // [m][k] linear, XOR-swizzled granules
  __shared__ __align__(16) unsigned short Bg[64 * 72];   // [n][k], 144B stride
  __shared__ __align__(16) unsigned short Bu[64 * 72];
  __shared__ int toks[128];

  if (t < 128) {
    int r = mt * 128 + t;
    toks[t] = tok_list[e * CAPE + (r < ne ? r : 0)];
  }
  __syncthreads();

  f32x4 z4 = {0.f, 0.f, 0.f, 0.f};
  f32x4 gacc[4][2], uacc[4][2];
  #pragma unroll
  for (int i = 0; i < 4; ++i)
    #pragma unroll
    for (int j = 0; j < 2; ++j) { gacc[i][j] = z4; uacc[i][j] = z4; }

  const size_t wbase = (size_t)e * HD * FD + (size_t)nt * 64;
  const int nc = t & 15, kc = t >> 4;

  for (int kt = 0; kt < HD / 64; ++kt) {
    const int k0 = kt * 64;
    // --- A: global_load_lds direct, source-swizzled so reads can XOR-deswizzle
    #pragma unroll
    for (int i = 0; i < 4; ++i) {
      const int inst = wid * 4 + i;
      const int G = inst * 64 + lane;
      const int m = G >> 3, gg = G & 7;
      const unsigned short* src = xb + (size_t)toks[m] * HD + k0 + 8 * (gg ^ (m & 7));
      load_lds16(src, &A[inst * 512]);
    }
    // --- B gate: transpose-stage f32 -> bf16 [n][k]
    {
      const float* pg = wg + wbase + (size_t)(k0 + kc * 4) * FD + nc * 4;
      float4 r0 = *(const float4*)(pg);
      float4 r1 = *(const float4*)(pg + FD);
      float4 r2 = *(const float4*)(pg + 2 * FD);
      float4 r3 = *(const float4*)(pg + 3 * FD);
      *(ushort4*)&Bg[(nc*4+0)*72 + kc*4] = make_ushort4(f2bf(r0.x), f2bf(r1.x), f2bf(r2.x), f2bf(r3.x));
      *(ushort4*)&Bg[(nc*4+1)*72 + kc*4] = make_ushort4(f2bf(r0.y), f2bf(r1.y), f2bf(r2.y), f2bf(r3.y));
      *(ushort4*)&Bg[(nc*4+2)*72 + kc*4] = make_ushort4(f2bf(r0.z), f2bf(r1.z), f2bf(r2.z), f2bf(r3.z));
      *(ushort4*)&Bg[(nc*4+3)*72 + kc*4] = make_ushort4(f2bf(r0.w), f2bf(r1.w), f2bf(r2.w), f2bf(r3.w));
    }
    // --- B up
    {
      const float* pu = wu + wbase + (size_t)(k0 + kc * 4) * FD + nc * 4;
      float4 r0 = *(const float4*)(pu);
      float4 r1 = *(const float4*)(pu + FD);
      float4 r2 = *(const float4*)(pu + 2 * FD);
      float4 r3 = *(const float4*)(pu + 3 * FD);
      *(ushort4*)&Bu[(nc*4+0)*72 + kc*4] = make_ushort4(f2bf(r0.x), f2bf(r1.x), f2bf(r2.x), f2bf(r3.x));
      *(ushort4*)&Bu[(nc*4+1)*72 + kc*4] = make_ushort4(f2bf(r0.y), f2bf(r1.y), f2bf(r2.y), f2bf(r3.y));
      *(ushort4*)&Bu[(nc*4+2)*72 + kc*4] = make_ushort4(f2bf(r0.z), f2bf(r1.z), f2bf(r2.z), f2bf(r3.z));
      *(ushort4*)&Bu[(nc*4+3)*72 + kc*4] = make_ushort4(f2bf(r0.w), f2bf(r1.w), f2bf(r2.w), f2bf(r3.w));
    }
    __syncthreads();
    #pragma unroll
    for (int ks = 0; ks < 2; ++ks) {
      bf16x8 af[4];
      #pragma unroll
      for (int mf = 0; mf < 4; ++mf) {
        int row = wr * 64 + mf * 16 + (lane & 15);
        int byte = row * 128 + (lane >> 4) * 16 + ks * 64;
        byte ^= (row & 7) << 4;
        af[mf] = *(const bf16x8*)((const char*)A + byte);
      }
      #pragma unroll
      for (int nf = 0; nf < 2; ++nf) {
        int n = wc * 32 + nf * 16 + (lane & 15);
        int off = n * 72 + (lane >> 4) * 8 + ks * 32;
        bf16x8 bgf = *(const bf16x8*)&Bg[off];
        bf16x8 bum = *(const bf16x8*)&Bu[off];
        #pragma unroll
        for (int mf = 0; mf < 4; ++mf) {
          gacc[mf][nf] = __builtin_amdgcn_mfma_f32_16x16x32_bf16(af[mf], bgf, gacc[mf][nf], 0, 0, 0);
          uacc[mf][nf] = __builtin_amdgcn_mfma_f32_16x16x32_bf16(af[mf], bum, uacc[mf][nf], 0, 0, 0);
        }
      }
    }
    __syncthreads();
  }
  // epilogue: hmid = silu(g)*u   (D layout: col=lane&15, row=4*(lane>>4)+reg)
  const size_t hbase = (size_t)e * CAPE + (size_t)mt * 128;
  #pragma unroll
  for (int mf = 0; mf < 4; ++mf) {
    #pragma unroll
    for (int nf = 0; nf < 2; ++nf) {
      #pragma unroll
      for (int r = 0; r < 4; ++r) {
        int row = wr * 64 + mf * 16 + (lane >> 4) * 4 + r;
        int c = nt * 64 + wc * 32 + nf * 16 + (lane & 15);
        float gv = gacc[mf][nf][r], uv = uacc[mf][nf][r];
        float hv = gv / (1.f + expf(-gv)) * uv;
        hmid[(hbase + row) * FD + c] = f2bf(hv);
      }
    }
  }
}

// ---------------- Kernel 4: down GEMM + weighted scatter-add ----------------
__global__ __launch_bounds__(256) void down_kernel(
    const unsigned short* __restrict__ hmid,
    const float* __restrict__ wd,
    const int* __restrict__ cnt, const int* __restrict__ tok_list,
    const float* __restrict__ w_list, float* __restrict__ out)
{
  const int nt = blockIdx.x, mt = blockIdx.y, e = blockIdx.z;
  int ne = cnt[e]; ne = ne < CAPE ? ne : CAPE;
  if (mt * 128 >= ne) return;
  const int t = threadIdx.x, lane = t & 63, wid = t >> 6;
  const int wr = wid >> 1, wc = wid & 1;

  __shared__ __align__(16) unsigned short A[128 * 64];
  __shared__ __align__(16) unsigned short Bd[64 * 72];
  __shared__ int toks[128];
  __shared__ float wts[128];

  if (t < 128) {
    int r = mt * 128 + t;
    bool vv = r < ne;
    toks[t] = vv ? tok_list[e * CAPE + r] : 0;
    wts[t]  = vv ? w_list[e * CAPE + r] : 0.f;
  }

  f32x4 z4 = {0.f, 0.f, 0.f, 0.f};
  f32x4 dacc[4][2];
  #pragma unroll
  for (int i = 0; i < 4; ++i)
    #pragma unroll
    for (int j = 0; j < 2; ++j) dacc[i][j] = z4;

  const size_t wbase = (size_t)e * FD * HD + (size_t)nt * 64;
  const size_t arow = (size_t)e * CAPE + (size_t)mt * 128;
  const int nc = t & 15, kc = t >> 4;

  for (int kt = 0; kt < FD / 64; ++kt) {
    const int k0 = kt * 64;
    #pragma unroll
    for (int i = 0; i < 4; ++i) {
      const int inst = wid * 4 + i;
      const int G = inst * 64 + lane;
      const int m = G >> 3, gg = G & 7;
      const unsigned short* src = hmid + (arow + m) * FD + k0 + 8 * (gg ^ (m & 7));
      load_lds16(src, &A[inst * 512]);
    }
    {
      const float* pd = wd + wbase + (size_t)(k0 + kc * 4) * HD + nc * 4;
      float4 r0 = *(const float4*)(pd);
      float4 r1 = *(const float4*)(pd + HD);
      float4 r2 = *(const float4*)(pd + 2 * HD);
      float4 r3 = *(const float4*)(pd + 3 * HD);
      *(ushort4*)&Bd[(nc*4+0)*72 + kc*4] = make_ushort4(f2bf(r0.x), f2bf(r1.x), f2bf(r2.x), f2bf(r3.x));
      *(ushort4*)&Bd[(nc*4+1)*72 + kc*4] = make_ushort4(f2bf(r0.y), f2bf(r1.y), f2bf(r2.y), f2bf(r3.y));
      *(ushort4*)&Bd[(nc*4+2)*72 + kc*4] = make_ushort4(f2bf(r0.z), f2bf(r1.z), f2bf(r2.z), f2bf(r3.z));
      *(ushort4*)&Bd[(nc*4+3)*72 + kc*4] = make_ushort4(f2bf(r0.w), f2bf(r1.w), f2bf(r2.w), f2bf(r3.w));
    }
    __syncthreads();
    #pragma unroll
    for (int ks = 0; ks < 2; ++ks) {
      bf16x8 af[4];
      #pragma unroll
      for (int mf = 0; mf < 4; ++mf) {
        int row = wr * 64 + mf * 16 + (lane & 15);
        int byte = row * 128 + (lane >> 4) * 16 + ks * 64;
        byte ^= (row & 7) << 4;
        af[mf] = *(const bf16x8*)((const char*)A + byte);
      }
      #pragma unroll
      for (int nf = 0; nf < 2; ++nf) {
        int n = wc * 32 + nf * 16 + (lane & 15);
        int off = n * 72 + (lane >> 4) * 8 + ks * 32;
        bf16x8 bdf = *(const bf16x8*)&Bd[off];
        #pragma unroll
        for (int mf = 0; mf < 4; ++mf)
          dacc[mf][nf] = __builtin_amdgcn_mfma_f32_16x16x32_bf16(af[mf], bdf, dacc[mf][nf], 0, 0, 0);
      }
    }
    __syncthreads();
  }
  // epilogue: weighted atomic scatter-add
  #pragma unroll
  for (int mf = 0; mf < 4; ++mf) {
    #pragma unroll
    for (int nf = 0; nf < 2; ++nf) {
      int c = nt * 64 + wc * 32 + nf * 16 + (lane & 15);
      #pragma unroll
      for (int r = 0; r < 4; ++r) {
        int row = wr * 64 + mf * 16 + (lane >> 4) * 4 + r;
        if (mt * 128 + row < ne) {
          int tok = toks[row];
          float w = wts[row];
          atomicAdd(&out[(size_t)tok * HD + c], w * dacc[mf][nf][r]);
        }
      }
    }
  }
}

extern "C" void kernel_launch(void* const* d_in, const int* in_sizes, int n_in,
                              void* d_out, int out_size, void* d_ws, size_t ws_size,
                              hipStream_t stream) {
  const float* x  = (const float*)d_in[0];
  const float* rw = (const float*)d_in[1];
  const float* wg = (const float*)d_in[2];
  const float* wu = (const float*)d_in[3];
  const float* wd = (const float*)d_in[4];
  float* out = (float*)d_out;

  char* ws = (char*)d_ws;
  unsigned short* xb   = (unsigned short*)ws;            // 8,388,608 B
  int* cnt             = (int*)(ws + 8388608);           // 256 B
  int* tok_list        = (int*)(ws + 8388864);           // 131,072 B
  float* w_list        = (float*)(ws + 8519936);         // 131,072 B
  unsigned short* hmid = (unsigned short*)(ws + 8651008);// 50,331,648 B

  hipMemsetAsync(d_out, 0, (size_t)out_size * sizeof(float), stream);
  hipMemsetAsync(cnt, 0, NEXP * sizeof(int), stream);

  router_kernel<<<T_TOK / 4, 256, 0, stream>>>(x, rw, cnt, tok_list, w_list);
  cvt_kernel<<<(T_TOK * HD / 4) / 256, 256, 0, stream>>>(x, xb);
  gateup_kernel<<<dim3(FD / 64, CAPE / 128, NEXP), 256, 0, stream>>>(xb, wg, wu, cnt, tok_list, hmid);
  down_kernel<<<dim3(HD / 64, CAPE / 128, NEXP), 256, 0, stream>>>(hmid, wd, cnt, tok_list, w_list, out);
}